// Round 1
// baseline (292.840 us; speedup 1.0000x reference)
//
#include <hip/hip_runtime.h>
#include <hip/hip_bf16.h>
#include <math.h>

// Problem constants
#define BH 2
#define HH 96
#define WW 96
#define CC 128
#define KD 64
#define OD 128
#define KSZ 7
#define PADR 3
#define NPIX (BH*HH*WW)   // 18432

// ---------------------------------------------------------------------------
// Generic small-N projection GEMM: out[M,N] = X[M,128] @ W[128,N] + b (+ReLU)
// Block = 256 threads, BM rows per block. X tile staged in LDS; W read via
// L1 (coalesced across tc, broadcast across tr). LDS reads are wave-uniform
// broadcasts (no bank conflicts).
// ---------------------------------------------------------------------------
template<int N, int BM, bool RELU>
__global__ __launch_bounds__(256) void proj_kernel(
    const float* __restrict__ X, const float* __restrict__ Wt,
    const float* __restrict__ bias, float* __restrict__ out)
{
    constexpr int K = 128;
    __shared__ float Xs[BM][K];

    const int tid  = threadIdx.x;
    const int row0 = blockIdx.x * BM;

    // Stage X tile (BM x 128 floats) into LDS, float4-vectorized, coalesced.
    constexpr int TOT4 = BM * K / 4;
    const float4* Xg  = reinterpret_cast<const float4*>(X + (size_t)row0 * K);
    float4*       Xs4 = reinterpret_cast<float4*>(&Xs[0][0]);
    #pragma unroll
    for (int i = 0; i < TOT4 / 256; ++i)
        Xs4[tid + 256 * i] = Xg[tid + 256 * i];
    __syncthreads();

    constexpr int TR  = 256 / N;   // thread-rows
    constexpr int RPT = BM / TR;   // rows per thread
    const int tc = tid % N;
    const int tr = tid / N;

    float acc[RPT];
    #pragma unroll
    for (int i = 0; i < RPT; ++i) acc[i] = 0.f;

    #pragma unroll 4
    for (int kk = 0; kk < K; ++kk) {
        const float w = Wt[kk * N + tc];
        #pragma unroll
        for (int i = 0; i < RPT; ++i)
            acc[i] += Xs[tr + TR * i][kk] * w;
    }

    const float bv = bias[tc];
    #pragma unroll
    for (int i = 0; i < RPT; ++i) {
        float v = acc[i] + bv;
        if (RELU) v = fmaxf(v, 0.f);
        out[(size_t)(row0 + tr + TR * i) * N + tc] = v;
    }
}

// ---------------------------------------------------------------------------
// Neighborhood attention: one wave (64 lanes) per pixel.
// Score phase: lanes span KD=64 dims; per neighbor a coalesced 256B k-row
// load + wave shuffle-reduction. OOB neighbors -> -inf (padding mask).
// Softmax across lanes 0..48. PV phase: lanes span C=128 (2 ch/lane),
// scores broadcast via __shfl. All control flow is wave-uniform.
// ---------------------------------------------------------------------------
__global__ __launch_bounds__(256) void attn_kernel(
    const float* __restrict__ q, const float* __restrict__ k,
    const float* __restrict__ V, float* __restrict__ O)
{
    const int wave = (blockIdx.x * blockDim.x + threadIdx.x) >> 6;
    const int lane = threadIdx.x & 63;
    if (wave >= NPIX) return;

    const int b  = wave / (HH * WW);
    const int hw = wave % (HH * WW);
    const int h  = hw / WW;
    const int w  = hw % WW;

    const float qd = q[(size_t)wave * KD + lane];
    const float scale = 0.125f;   // 1/sqrt(KD)

    float myscore = -INFINITY;
    #pragma unroll
    for (int j = 0; j < 49; ++j) {
        const int y = h + j / 7 - PADR;
        const int x = w + j % 7 - PADR;
        const bool valid = (y >= 0 && y < HH && x >= 0 && x < WW);
        float p = 0.f;
        if (valid) p = qd * k[((size_t)(b * HH + y) * WW + x) * KD + lane];
        #pragma unroll
        for (int off = 32; off > 0; off >>= 1) p += __shfl_xor(p, off);
        const float s = valid ? p * scale : -INFINITY;
        if (lane == j) myscore = s;
    }

    // softmax over lanes (lanes 49..63 hold -inf -> exp = 0)
    float m = myscore;
    #pragma unroll
    for (int off = 32; off > 0; off >>= 1) m = fmaxf(m, __shfl_xor(m, off));
    const float e = expf(myscore - m);
    float sum = e;
    #pragma unroll
    for (int off = 32; off > 0; off >>= 1) sum += __shfl_xor(sum, off);
    const float p = e / sum;

    float acc0 = 0.f, acc1 = 0.f;
    #pragma unroll
    for (int j = 0; j < 49; ++j) {
        const float sj = __shfl(p, j);
        const int y = h + j / 7 - PADR;
        const int x = w + j % 7 - PADR;
        if (y >= 0 && y < HH && x >= 0 && x < WW) {
            const float* vr = V + ((size_t)(b * HH + y) * WW + x) * CC;
            acc0 += sj * vr[lane];
            acc1 += sj * vr[lane + 64];
        }
    }
    O[(size_t)wave * CC + lane]      = acc0;
    O[(size_t)wave * CC + lane + 64] = acc1;
}

extern "C" void kernel_launch(void* const* d_in, const int* in_sizes, int n_in,
                              void* d_out, int out_size, void* d_ws, size_t ws_size,
                              hipStream_t stream)
{
    const float* Q  = (const float*)d_in[0];
    const float* K  = (const float*)d_in[1];
    const float* V  = (const float*)d_in[2];
    const float* Wq = (const float*)d_in[3];
    const float* bq = (const float*)d_in[4];
    const float* Wk = (const float*)d_in[5];
    const float* bk = (const float*)d_in[6];
    const float* Wv = (const float*)d_in[7];
    const float* bv = (const float*)d_in[8];
    float* out = (float*)d_out;

    // workspace layout (all 512B-aligned)
    const size_t q_bytes = (size_t)NPIX * KD * sizeof(float);   // 4.72 MB
    float* q_ws   = (float*)d_ws;
    float* k_ws   = (float*)((char*)d_ws + q_bytes);
    float* att_ws = (float*)((char*)d_ws + 2 * q_bytes);        // NPIX*128 floats

    // 1-2) q/k projections: M=18432, N=64, BM=64 -> 288 blocks
    proj_kernel<KD, 64, false><<<NPIX / 64, 256, 0, stream>>>(Q, Wq, bq, q_ws);
    proj_kernel<KD, 64, false><<<NPIX / 64, 256, 0, stream>>>(K, Wk, bk, k_ws);

    // 3) neighborhood attention: 1 wave/pixel, 4 waves/block
    attn_kernel<<<NPIX / 4, 256, 0, stream>>>(q_ws, k_ws, V, att_ws);

    // 4) output projection + bias + ReLU: N=128, BM=32 -> 576 blocks
    proj_kernel<OD, 32, true><<<NPIX / 32, 256, 0, stream>>>(att_ws, Wv, bv, out);
}

// Round 2
// 212.214 us; speedup vs baseline: 1.3799x; 1.3799x over previous
//
#include <hip/hip_runtime.h>
#include <hip/hip_bf16.h>
#include <math.h>

// Problem constants
#define BH 2
#define HH 96
#define WW 96
#define CC 128
#define KD 64
#define OD 128
#define PADR 3
#define NPIX (BH*HH*WW)   // 18432

// ---------------------------------------------------------------------------
// Projection GEMM, outer-product form: out[M,N] = X[M,128] @ W[128,N] + b.
// Block = 256 threads = 4 waves; block covers 64 rows; wave w owns columns
// [w*NC, w*NC+NC), NC = N/4. lane <-> row. Per kk: ONE conflict-free LDS
// read (Xs stride 129) feeds NC FMAs whose W operand comes from scalar
// (SGPR) loads -- c0 is forced wave-uniform via readfirstlane.
// ---------------------------------------------------------------------------
template<int N, bool RELU>
__global__ __launch_bounds__(256) void proj_kernel(
    const float* __restrict__ X, const float* __restrict__ Wt,
    const float* __restrict__ bias, float* __restrict__ out)
{
    constexpr int NC = N / 4;
    __shared__ float Xs[64][129];

    const int tid  = threadIdx.x;
    const int lane = tid & 63;
    const int row0 = blockIdx.x * 64;

    // Stage X tile: 64 rows x 128 floats, coalesced float4 global reads.
    {
        const float4* Xg = reinterpret_cast<const float4*>(X + (size_t)row0 * 128);
        #pragma unroll
        for (int i = 0; i < 8; ++i) {
            const int e = tid + 256 * i;     // float4 index 0..2047
            const float4 v = Xg[e];
            const int r = e >> 5;            // 32 float4 per row
            const int c = (e & 31) << 2;
            Xs[r][c]   = v.x; Xs[r][c+1] = v.y;
            Xs[r][c+2] = v.z; Xs[r][c+3] = v.w;
        }
    }
    __syncthreads();

    // wave-uniform column base -> W loads become scalar loads
    const int c0 = __builtin_amdgcn_readfirstlane((tid >> 6) * NC);

    float acc[NC];
    #pragma unroll
    for (int i = 0; i < NC; ++i) acc[i] = 0.f;

    #pragma unroll 2
    for (int kk = 0; kk < 128; ++kk) {
        const float xv = Xs[lane][kk];              // 1 conflict-free LDS read
        const float* __restrict__ wrow = Wt + kk * N + c0;  // uniform address
        #pragma unroll
        for (int i = 0; i < NC; ++i)
            acc[i] = fmaf(xv, wrow[i], acc[i]);     // sgpr x vgpr fma
    }

    const float* __restrict__ brow = bias + c0;
    float* __restrict__ orow = out + (size_t)(row0 + lane) * N + c0;
    #pragma unroll
    for (int i = 0; i < NC; ++i) {
        float v = acc[i] + brow[i];
        if (RELU) v = fmaxf(v, 0.f);
        orow[i] = v;
    }
}

// ---------------------------------------------------------------------------
// Neighborhood attention v2: one wave per pixel.
// Score phase: q-row in SGPRs (wave-uniform scalar loads); lane j (<49)
// computes its OWN neighbor's full 64-dim dot with float4 k loads --
// no cross-lane ops. Softmax: 2 shuffle chains. PV: lanes span C=128 as
// float2, scores broadcast via __shfl (independent, pipelined).
// ---------------------------------------------------------------------------
__global__ __launch_bounds__(256) void attn_kernel(
    const float* __restrict__ q, const float* __restrict__ k,
    const float* __restrict__ V, float* __restrict__ O)
{
    const int wave = (blockIdx.x * blockDim.x + threadIdx.x) >> 6;
    const int lane = threadIdx.x & 63;
    if (wave >= NPIX) return;

    const int wv = __builtin_amdgcn_readfirstlane(wave);
    const int b  = wv / (HH * WW);
    const int hw = wv % (HH * WW);
    const int h  = hw / WW;
    const int w  = hw % WW;

    const float* __restrict__ qrow = q + (size_t)wv * KD;   // wave-uniform

    // ---- score for my neighbor (lane = j) ----
    const int jy = lane / 7;
    const int jx = lane % 7;
    const int y  = h + jy - PADR;
    const int x  = w + jx - PADR;
    const bool valid = (lane < 49) & ((unsigned)y < HH) & ((unsigned)x < WW);

    float sc = 0.f;
    if (valid) {
        const float4* __restrict__ kr =
            reinterpret_cast<const float4*>(k + ((size_t)(b * HH + y) * WW + x) * KD);
        #pragma unroll
        for (int d4 = 0; d4 < KD / 4; ++d4) {
            const float4 kv = kr[d4];
            sc = fmaf(qrow[4*d4+0], kv.x, sc);
            sc = fmaf(qrow[4*d4+1], kv.y, sc);
            sc = fmaf(qrow[4*d4+2], kv.z, sc);
            sc = fmaf(qrow[4*d4+3], kv.w, sc);
        }
    }
    const float ms = valid ? sc * 0.125f : -INFINITY;   // 1/sqrt(64)

    // ---- softmax across lanes (lanes >=49 / OOB contribute 0) ----
    float m = ms;
    #pragma unroll
    for (int off = 32; off > 0; off >>= 1) m = fmaxf(m, __shfl_xor(m, off));
    const float e = expf(ms - m);
    float sum = e;
    #pragma unroll
    for (int off = 32; off > 0; off >>= 1) sum += __shfl_xor(sum, off);
    const float p = e / sum;

    // ---- PV: lanes span C=128 as float2 ----
    float2 acc = make_float2(0.f, 0.f);
    #pragma unroll
    for (int j = 0; j < 49; ++j) {
        const float sj = __shfl(p, j);               // all lanes execute
        const int yy = h + j / 7 - PADR;
        const int xx = w + j % 7 - PADR;
        if (yy >= 0 && yy < HH && xx >= 0 && xx < WW) {   // wave-uniform branch
            const float2* __restrict__ vr = reinterpret_cast<const float2*>(
                V + ((size_t)(b * HH + yy) * WW + xx) * CC);
            const float2 v2 = vr[lane];
            acc.x = fmaf(sj, v2.x, acc.x);
            acc.y = fmaf(sj, v2.y, acc.y);
        }
    }
    reinterpret_cast<float2*>(O + (size_t)wv * CC)[lane] = acc;
}

extern "C" void kernel_launch(void* const* d_in, const int* in_sizes, int n_in,
                              void* d_out, int out_size, void* d_ws, size_t ws_size,
                              hipStream_t stream)
{
    const float* Q  = (const float*)d_in[0];
    const float* K  = (const float*)d_in[1];
    const float* V  = (const float*)d_in[2];
    const float* Wq = (const float*)d_in[3];
    const float* bq = (const float*)d_in[4];
    const float* Wk = (const float*)d_in[5];
    const float* bk = (const float*)d_in[6];
    const float* Wv = (const float*)d_in[7];
    const float* bv = (const float*)d_in[8];
    float* out = (float*)d_out;

    const size_t q_bytes = (size_t)NPIX * KD * sizeof(float);   // 4.72 MB
    float* q_ws   = (float*)d_ws;
    float* k_ws   = (float*)((char*)d_ws + q_bytes);
    float* att_ws = (float*)((char*)d_ws + 2 * q_bytes);        // NPIX*128 floats

    // q/k projections: 288 blocks each, 64 rows/block
    proj_kernel<KD, false><<<NPIX / 64, 256, 0, stream>>>(Q, Wq, bq, q_ws);
    proj_kernel<KD, false><<<NPIX / 64, 256, 0, stream>>>(K, Wk, bk, k_ws);

    // neighborhood attention: 1 wave/pixel, 4 waves/block
    attn_kernel<<<NPIX / 4, 256, 0, stream>>>(q_ws, k_ws, V, att_ws);

    // output projection + bias + ReLU
    proj_kernel<OD, true><<<NPIX / 64, 256, 0, stream>>>(att_ws, Wv, bv, out);
}

// Round 3
// 165.686 us; speedup vs baseline: 1.7674x; 1.2808x over previous
//
#include <hip/hip_runtime.h>
#include <math.h>

// Problem constants
#define BH 2
#define HH 96
#define WW 96
#define CC 128
#define KD 64
#define OD 128

// Attention tile geometry
#define TH 8            // tile rows (pixels)
#define TW 4            // tile cols (pixels)  -> 32 px/block
#define NH 140          // real halo pixels: (8+6)*(4+6)
#define NHP 160         // padded halo (10 n-tiles of 16, 5 k-steps of 32)

typedef __attribute__((ext_vector_type(8))) short short8;
typedef __attribute__((ext_vector_type(4))) float f32x4;

__device__ __forceinline__ unsigned short f2bf(float f) {
    union { float f; unsigned u; } a; a.f = f;
    return (unsigned short)((a.u + 0x7FFFu + ((a.u >> 16) & 1u)) >> 16);
}

// ---------------------------------------------------------------------------
// prep: W[128][N] fp32 -> WT[N][128] bf16 (B-operand friendly layout)
// ---------------------------------------------------------------------------
__global__ __launch_bounds__(256) void prep_kernel(
    const float* __restrict__ Wq, const float* __restrict__ Wk,
    const float* __restrict__ Wv, unsigned short* __restrict__ wbase)
{
    unsigned short* WqT = wbase;
    unsigned short* WkT = wbase + 8192;
    unsigned short* WvT = wbase + 16384;
    const int e = blockIdx.x * 256 + threadIdx.x;      // 0..32767
    if (e < 8192)       { WqT[e] = f2bf(Wq[(e & 127) * 64  + (e >> 7)]); }
    else if (e < 16384) { int t = e - 8192;  WkT[t] = f2bf(Wk[(t & 127) * 64  + (t >> 7)]); }
    else                { int t = e - 16384; WvT[t] = f2bf(Wv[(t & 127) * 128 + (t >> 7)]); }
}

// ---------------------------------------------------------------------------
// proj: Y[M,64] = bf16( X[M,128] @ W + b ).  Block=256 (4 waves), 64 rows.
// Wave = one 16-row m-tile, all 4 n-tiles, K=128 (4 MFMA k-steps).
// ---------------------------------------------------------------------------
__global__ __launch_bounds__(256) void proj_kernel(
    const float* __restrict__ X, const unsigned short* __restrict__ WT,
    const float* __restrict__ bias, unsigned short* __restrict__ Y)
{
    __shared__ unsigned short Xs[64 * 136];    // stride 136 bf16 (16B-aligned rows)
    const int tid  = threadIdx.x;
    const int lane = tid & 63;
    const int wv   = tid >> 6;
    const int row0 = blockIdx.x * 64;

    // stage X tile 64x128 fp32 -> bf16 pairs (conflict-free b32 LDS writes)
    #pragma unroll
    for (int i = 0; i < 16; ++i) {
        const int idx = tid + 256 * i;         // 0..4095  (64 rows x 64 pairs)
        const int r = idx >> 6, c2 = idx & 63;
        const float2 v = reinterpret_cast<const float2*>(X + (size_t)(row0 + r) * 128)[c2];
        union { unsigned short h[2]; unsigned u; } pk;
        pk.h[0] = f2bf(v.x); pk.h[1] = f2bf(v.y);
        reinterpret_cast<unsigned*>(Xs)[r * 68 + c2] = pk.u;
    }
    __syncthreads();

    const int qd = lane >> 4, m = lane & 15;
    short8 afr[4];
    #pragma unroll
    for (int ks = 0; ks < 4; ++ks)
        afr[ks] = *reinterpret_cast<const short8*>(&Xs[(wv * 16 + m) * 136 + ks * 32 + qd * 8]);

    #pragma unroll
    for (int n = 0; n < 4; ++n) {
        f32x4 acc = {};
        #pragma unroll
        for (int ks = 0; ks < 4; ++ks) {
            const short8 bfr = *reinterpret_cast<const short8*>(
                WT + (n * 16 + m) * 128 + ks * 32 + qd * 8);
            acc = __builtin_amdgcn_mfma_f32_16x16x32_bf16(afr[ks], bfr, acc, 0, 0, 0);
        }
        const int col = n * 16 + m;
        const float bb = bias[col];
        #pragma unroll
        for (int r = 0; r < 4; ++r) {
            const int grow = row0 + wv * 16 + qd * 4 + r;
            Y[(size_t)grow * 64 + col] = f2bf(acc[r] + bb);
        }
    }
}

// ---------------------------------------------------------------------------
// Fused neighborhood attention + output projection.
// Block = 128 threads (2 waves), tile = 8x4 pixels, halo 14x10 (pad to 160).
// Phases: stage q/k -> score MFMA -> mask+softmax (in-reg) -> P,V -> LDS
//         -> PV MFMA -> att -> LDS -> out-proj MFMA + bias + relu -> global.
// ---------------------------------------------------------------------------
#define PS_STRIDE 168
#define QS_STRIDE 72
#define KS_STRIDE 72
#define VT_STRIDE 168
#define AS_STRIDE 136
#define PS_OFF 0        // 32*168  = 5376
#define QS_OFF 5376     // 32*72   = 2304 -> 7680
#define KS_OFF 7680     // 160*72  = 11520 -> 19200
#define VT_OFF 5376     // 128*168 = 21504 -> 26880 (overlaps dead q_s/k_s)
#define AS_OFF 0        // 32*136  = 4352  (overlays dead P_s)
#define LDS_N 26880     // ushort -> 53760 B

__global__ __launch_bounds__(128) void attn_kernel(
    const unsigned short* __restrict__ q, const unsigned short* __restrict__ k,
    const float* __restrict__ V, const unsigned short* __restrict__ WvT,
    const float* __restrict__ bv, float* __restrict__ out)
{
    __shared__ unsigned short lds[LDS_N];
    const int tid  = threadIdx.x;
    const int lane = tid & 63;
    const int wv   = tid >> 6;

    const int bid  = blockIdx.x;            // 576
    const int bimg = bid / 288;
    const int tidx = bid % 288;
    const int ty = tidx / 24, tx = tidx % 24;   // 12 x 24 tiles
    const int y0 = ty * TH, x0 = tx * TW;

    unsigned* ldsu = reinterpret_cast<unsigned*>(lds);
    const unsigned* qgu = reinterpret_cast<const unsigned*>(q);
    const unsigned* kgu = reinterpret_cast<const unsigned*>(k);

    // ---- stage q_s: 32 rows x 32 uint (bf16 pairs) ----
    #pragma unroll
    for (int i = 0; i < 8; ++i) {
        const int idx = tid + 128 * i;          // 0..1023
        const int r = idx >> 5, c2 = idx & 31;
        const int py = r >> 2, px = r & 3;
        const int gp = (bimg * HH + y0 + py) * WW + (x0 + px);
        ldsu[QS_OFF / 2 + r * 36 + c2] = qgu[gp * 32 + c2];
    }
    // ---- stage k_s: 160 halo rows x 32 uint (OOB/pad rows -> 0) ----
    #pragma unroll 8
    for (int i = 0; i < 40; ++i) {
        const int idx = tid + 128 * i;          // 0..5119
        const int r = idx >> 5, c2 = idx & 31;
        const int hy = (r * 6554) >> 16;        // r / 10
        const int hx = r - hy * 10;
        const int iy = y0 - 3 + hy, ix = x0 - 3 + hx;
        unsigned val = 0;
        if (((unsigned)iy < HH) & ((unsigned)ix < WW) & (r < NH))
            val = kgu[((bimg * HH + iy) * WW + ix) * 32 + c2];
        ldsu[KS_OFF / 2 + r * 36 + c2] = val;
    }
    __syncthreads();

    const int qd = lane >> 4, m = lane & 15;

    // ---- score MFMA: S[32 px, 160 halo] = q[32,64] @ k_halo^T ----
    short8 qa[2];
    #pragma unroll
    for (int ks = 0; ks < 2; ++ks)
        qa[ks] = *reinterpret_cast<const short8*>(
            &lds[QS_OFF + (wv * 16 + m) * QS_STRIDE + ks * 32 + qd * 8]);

    f32x4 sc[10];
    #pragma unroll
    for (int n = 0; n < 10; ++n) {
        f32x4 a = {};
        #pragma unroll
        for (int ks = 0; ks < 2; ++ks) {
            const short8 bfr = *reinterpret_cast<const short8*>(
                &lds[KS_OFF + (n * 16 + m) * KS_STRIDE + ks * 32 + qd * 8]);
            a = __builtin_amdgcn_mfma_f32_16x16x32_bf16(qa[ks], bfr, a, 0, 0, 0);
        }
        sc[n] = a;
    }
    __syncthreads();   // all waves done reading q_s/k_s

    // ---- mask (+image bounds, window membership) and softmax ----
    float mx[4] = {-INFINITY, -INFINITY, -INFINITY, -INFINITY};
    #pragma unroll
    for (int n = 0; n < 10; ++n) {
        const int h  = n * 16 + m;
        const int hy = (h * 6554) >> 16;
        const int hx = h - hy * 10;
        const int iy = y0 - 3 + hy, ix = x0 - 3 + hx;
        const bool imgok = ((unsigned)iy < HH) & ((unsigned)ix < WW);
        #pragma unroll
        for (int r = 0; r < 4; ++r) {
            const int p  = wv * 16 + qd * 4 + r;   // pixel 0..31
            const int py = p >> 2, px = p & 3;
            const bool ok = imgok & ((unsigned)(hy - py) <= 6u) & ((unsigned)(hx - px) <= 6u);
            const float s = ok ? sc[n][r] * 0.125f : -INFINITY;
            sc[n][r] = s;
            mx[r] = fmaxf(mx[r], s);
        }
    }
    #pragma unroll
    for (int r = 0; r < 4; ++r)
        #pragma unroll
        for (int off = 1; off < 16; off <<= 1)
            mx[r] = fmaxf(mx[r], __shfl_xor(mx[r], off));

    float sum[4] = {0.f, 0.f, 0.f, 0.f};
    #pragma unroll
    for (int n = 0; n < 10; ++n)
        #pragma unroll
        for (int r = 0; r < 4; ++r) {
            const float e = __expf(sc[n][r] - mx[r]);
            sc[n][r] = e;
            sum[r] += e;
        }
    #pragma unroll
    for (int r = 0; r < 4; ++r) {
        #pragma unroll
        for (int off = 1; off < 16; off <<= 1)
            sum[r] += __shfl_xor(sum[r], off);
        sum[r] = 1.0f / sum[r];
    }

    // ---- write P (bf16) : rows = own m-tile only ----
    #pragma unroll
    for (int n = 0; n < 10; ++n)
        #pragma unroll
        for (int r = 0; r < 4; ++r) {
            const int row = wv * 16 + qd * 4 + r;
            lds[PS_OFF + row * PS_STRIDE + n * 16 + m] = f2bf(sc[n][r] * sum[r]);
        }

    // ---- stage V transposed: Vt[ch=tid][halo] bf16 (over dead q_s/k_s) ----
    #pragma unroll 4
    for (int r = 0; r < NH; ++r) {
        const int hy = (r * 6554) >> 16;
        const int hx = r - hy * 10;
        const int iy = y0 - 3 + hy, ix = x0 - 3 + hx;
        float v = 0.f;
        if (((unsigned)iy < HH) & ((unsigned)ix < WW))
            v = V[(size_t)((bimg * HH + iy) * WW + ix) * CC + tid];
        lds[VT_OFF + tid * VT_STRIDE + r] = f2bf(v);
    }
    #pragma unroll
    for (int r = NH; r < NHP; ++r)
        lds[VT_OFF + tid * VT_STRIDE + r] = 0;
    __syncthreads();

    // ---- PV MFMA: att[32,128] = P[32,160] @ V[160,128] ----
    short8 pa[5];
    #pragma unroll
    for (int ks = 0; ks < 5; ++ks)
        pa[ks] = *reinterpret_cast<const short8*>(
            &lds[PS_OFF + (wv * 16 + m) * PS_STRIDE + ks * 32 + qd * 8]);

    f32x4 oacc[8];
    #pragma unroll
    for (int n = 0; n < 8; ++n) {
        f32x4 a = {};
        #pragma unroll
        for (int ks = 0; ks < 5; ++ks) {
            const short8 bfr = *reinterpret_cast<const short8*>(
                &lds[VT_OFF + (n * 16 + m) * VT_STRIDE + ks * 32 + qd * 8]);
            a = __builtin_amdgcn_mfma_f32_16x16x32_bf16(pa[ks], bfr, a, 0, 0, 0);
        }
        oacc[n] = a;
    }
    __syncthreads();   // done reading P_s / Vt

    // ---- att -> LDS (bf16, A-layout source) ----
    #pragma unroll
    for (int n = 0; n < 8; ++n)
        #pragma unroll
        for (int r = 0; r < 4; ++r) {
            const int row = wv * 16 + qd * 4 + r;
            lds[AS_OFF + row * AS_STRIDE + n * 16 + m] = f2bf(oacc[n][r]);
        }
    __syncthreads();

    // ---- out-proj MFMA: out[32,128] = relu(att @ Wv + bv) ----
    short8 aa[4];
    #pragma unroll
    for (int ks = 0; ks < 4; ++ks)
        aa[ks] = *reinterpret_cast<const short8*>(
            &lds[AS_OFF + (wv * 16 + m) * AS_STRIDE + ks * 32 + qd * 8]);

    #pragma unroll
    for (int n = 0; n < 8; ++n) {
        f32x4 a = {};
        #pragma unroll
        for (int ks = 0; ks < 4; ++ks) {
            const short8 bfr = *reinterpret_cast<const short8*>(
                WvT + (n * 16 + m) * 128 + ks * 32 + qd * 8);
            a = __builtin_amdgcn_mfma_f32_16x16x32_bf16(aa[ks], bfr, a, 0, 0, 0);
        }
        const int col = n * 16 + m;
        const float bb = bv[col];
        #pragma unroll
        for (int r = 0; r < 4; ++r) {
            const int p  = wv * 16 + qd * 4 + r;
            const int py = p >> 2, px = p & 3;
            const size_t gp = (size_t)(bimg * HH + y0 + py) * WW + (x0 + px);
            out[gp * OD + col] = fmaxf(a[r] + bb, 0.f);
        }
    }
}

extern "C" void kernel_launch(void* const* d_in, const int* in_sizes, int n_in,
                              void* d_out, int out_size, void* d_ws, size_t ws_size,
                              hipStream_t stream)
{
    const float* Q  = (const float*)d_in[0];
    const float* K  = (const float*)d_in[1];
    const float* V  = (const float*)d_in[2];
    const float* Wq = (const float*)d_in[3];
    const float* bq = (const float*)d_in[4];
    const float* Wk = (const float*)d_in[5];
    const float* bk = (const float*)d_in[6];
    const float* Wv = (const float*)d_in[7];
    const float* bv = (const float*)d_in[8];
    float* out = (float*)d_out;

    unsigned short* wbase = (unsigned short*)d_ws;
    unsigned short* WqT  = wbase;                  // 8192  bf16
    unsigned short* WkT  = wbase + 8192;           // 8192  bf16
    unsigned short* WvT  = wbase + 16384;          // 16384 bf16
    unsigned short* q_ws = wbase + 32768;          // 18432*64 bf16
    unsigned short* k_ws = q_ws + (size_t)18432 * 64;

    prep_kernel<<<128, 256, 0, stream>>>(Wq, Wk, Wv, wbase);
    proj_kernel<<<288, 256, 0, stream>>>(Q, WqT, bq, q_ws);
    proj_kernel<<<288, 256, 0, stream>>>(K, WkT, bk, k_ws);
    attn_kernel<<<576, 128, 0, stream>>>(q_ws, k_ws, V, WvT, bv, out);
}

// Round 4
// 145.238 us; speedup vs baseline: 2.0163x; 1.1408x over previous
//
#include <hip/hip_runtime.h>
#include <math.h>

// Problem constants
#define BH 2
#define HH 96
#define WW 96
#define CC 128
#define KD 64
#define OD 128
#define NPIX (BH*HH*WW)

// Attention tile geometry
#define TH 8            // tile rows (pixels)
#define TW 4            // tile cols (pixels)  -> 32 px/block
#define NH 140          // real halo pixels: (8+6)*(4+6)
#define NHP 160         // padded halo (10 n-tiles of 16, 5 k-steps of 32)

#define NEGBIG (-3.0e38f)

typedef __attribute__((ext_vector_type(8))) short short8;
typedef __attribute__((ext_vector_type(4))) float f32x4;

__device__ __forceinline__ unsigned short f2bf(float f) {
    union { float f; unsigned u; } a; a.f = f;
    return (unsigned short)((a.u + 0x7FFFu + ((a.u >> 16) & 1u)) >> 16);
}

// ---------------------------------------------------------------------------
// prep: W[128][N] fp32 -> WT[N][128] bf16, and V fp32 -> bf16 (same layout).
// bid < 128: W transposes. bid >= 128: V conversion (coalesced uint writes).
// ---------------------------------------------------------------------------
__global__ __launch_bounds__(256) void prep_kernel(
    const float* __restrict__ Wq, const float* __restrict__ Wk,
    const float* __restrict__ Wv, const float* __restrict__ V,
    unsigned short* __restrict__ wbase, unsigned* __restrict__ vbf_u)
{
    const int bid = blockIdx.x;
    const int tid = threadIdx.x;
    if (bid < 128) {
        unsigned short* WqT = wbase;
        unsigned short* WkT = wbase + 8192;
        unsigned short* WvT = wbase + 16384;
        const int e = bid * 256 + tid;                 // 0..32767
        if (e < 8192)       { WqT[e] = f2bf(Wq[(e & 127) * 64  + (e >> 7)]); }
        else if (e < 16384) { int t = e - 8192;  WkT[t] = f2bf(Wk[(t & 127) * 64  + (t >> 7)]); }
        else                { int t = e - 16384; WvT[t] = f2bf(Wv[(t & 127) * 128 + (t >> 7)]); }
    } else {
        // V: NPIX*128 floats -> bf16 pairs. 1152 blocks x 256 thr x 4 uints.
        const int idx = (bid - 128) * 256 + tid;       // 0..294911
        const float2* __restrict__ V2 = reinterpret_cast<const float2*>(V);
        #pragma unroll
        for (int j = 0; j < 4; ++j) {
            const int u = idx + j * 294912;
            const float2 v = V2[u];
            union { unsigned short h[2]; unsigned w; } pk;
            pk.h[0] = f2bf(v.x); pk.h[1] = f2bf(v.y);
            vbf_u[u] = pk.w;
        }
    }
}

// ---------------------------------------------------------------------------
// Fused q+k projection: Y[M,64] = bf16( X[M,128] @ W + b ).
// 576 blocks x 4 INDEPENDENT waves (no LDS, no barriers). Wave = 16 rows.
// Waves 0..1151 -> q, 1152..2303 -> k. A-frags via direct global float4
// loads + in-register bf16 convert; B-frags direct from L1-resident WT.
// ---------------------------------------------------------------------------
__global__ __launch_bounds__(256) void proj_kernel(
    const float* __restrict__ Q, const float* __restrict__ K,
    const unsigned short* __restrict__ wbase,
    const float* __restrict__ bq, const float* __restrict__ bk,
    unsigned short* __restrict__ q_ws, unsigned short* __restrict__ k_ws)
{
    const int tid  = threadIdx.x;
    const int lane = tid & 63;
    const int wv   = tid >> 6;
    const int gw   = blockIdx.x * 4 + wv;          // 0..2303
    const bool isq = gw < 1152;
    const int row0 = (isq ? gw : gw - 1152) * 16;

    const float* __restrict__ X   = isq ? Q : K;
    const unsigned short* __restrict__ WT = isq ? wbase : (wbase + 8192);
    const float* __restrict__ bias = isq ? bq : bk;
    unsigned short* __restrict__ Y = isq ? q_ws : k_ws;

    const int qd = lane >> 4, m = lane & 15;

    // A-frags: 4 k-steps, 8 fp32 each -> bf16
    short8 afr[4];
    #pragma unroll
    for (int ks = 0; ks < 4; ++ks) {
        const float4* __restrict__ src = reinterpret_cast<const float4*>(
            X + (size_t)(row0 + m) * 128 + ks * 32 + qd * 8);
        const float4 a0 = src[0], a1 = src[1];
        short8 f;
        f[0] = (short)f2bf(a0.x); f[1] = (short)f2bf(a0.y);
        f[2] = (short)f2bf(a0.z); f[3] = (short)f2bf(a0.w);
        f[4] = (short)f2bf(a1.x); f[5] = (short)f2bf(a1.y);
        f[6] = (short)f2bf(a1.z); f[7] = (short)f2bf(a1.w);
        afr[ks] = f;
    }

    #pragma unroll
    for (int n = 0; n < 4; ++n) {
        f32x4 acc = {};
        #pragma unroll
        for (int ks = 0; ks < 4; ++ks) {
            const short8 bfr = *reinterpret_cast<const short8*>(
                WT + (n * 16 + m) * 128 + ks * 32 + qd * 8);
            acc = __builtin_amdgcn_mfma_f32_16x16x32_bf16(afr[ks], bfr, acc, 0, 0, 0);
        }
        const int col = n * 16 + m;
        const float bb = bias[col];
        #pragma unroll
        for (int r = 0; r < 4; ++r)
            Y[(size_t)(row0 + qd * 4 + r) * 64 + col] = f2bf(acc[r] + bb);
    }
}

// ---------------------------------------------------------------------------
// Fused neighborhood attention + output projection.
// Block = 256 threads (4 waves): wave = (mt, nh); mt = m-tile (16 px),
// nh = n-half. Score: 5 n-tiles/wave; softmax partials merged via LDS;
// PV + out-proj: 4 n-tiles/wave. 4 barriers total.
// ---------------------------------------------------------------------------
#define PS_STRIDE 168
#define AS_STRIDE 136
#define QS_STRIDE 72
#define KS_STRIDE 72
#define VT_STRIDE 168
#define PS_OFF 0          // 32*168 = 5376
#define AS_OFF 5376       // 32*136 = 4352 -> 9728
#define SM_OFF 9728       // 128 floats = 256 sh -> 9984
#define QS_OFF 9984       // 32*72  = 2304 -> 12288
#define KS_OFF 12288      // 160*72 = 11520 -> 23808
#define VT_OFF 9984       // 128*168 = 21504 -> 31488 (overlays dead QS/KS)
#define LDS_N 31488       // ushort -> 62976 B -> 2 blocks/CU

__global__ __launch_bounds__(256) void attn_kernel(
    const unsigned short* __restrict__ q, const unsigned short* __restrict__ k,
    const unsigned short* __restrict__ vbf, const unsigned short* __restrict__ WvT,
    const float* __restrict__ bv, float* __restrict__ out)
{
    __shared__ unsigned short lds[LDS_N];
    const int tid  = threadIdx.x;
    const int lane = tid & 63;
    const int wv   = tid >> 6;
    const int mt   = wv & 1;       // m-tile
    const int nh   = wv >> 1;      // n-half

    const int bid  = blockIdx.x;   // 576
    const int bimg = bid / 288;
    const int tidx = bid % 288;
    const int ty = tidx / 24, tx = tidx % 24;
    const int y0 = ty * TH, x0 = tx * TW;

    unsigned* ldsu = reinterpret_cast<unsigned*>(lds);
    const unsigned* qgu = reinterpret_cast<const unsigned*>(q);
    const unsigned* kgu = reinterpret_cast<const unsigned*>(k);

    // ---- stage q_s: 32 rows x 32 uint ----
    #pragma unroll
    for (int i = 0; i < 4; ++i) {
        const int idx = tid + 256 * i;          // 0..1023
        const int r = idx >> 5, c2 = idx & 31;
        const int py = r >> 2, px = r & 3;
        const int gp = (bimg * HH + y0 + py) * WW + (x0 + px);
        ldsu[QS_OFF / 2 + r * 36 + c2] = qgu[gp * 32 + c2];
    }
    // ---- stage k_s: 160 halo rows x 32 uint (OOB/pad -> 0) ----
    #pragma unroll 5
    for (int i = 0; i < 20; ++i) {
        const int idx = tid + 256 * i;          // 0..5119
        const int r = idx >> 5, c2 = idx & 31;
        const int hy = (r * 6554) >> 16;        // r / 10
        const int hx = r - hy * 10;
        const int iy = y0 - 3 + hy, ix = x0 - 3 + hx;
        unsigned val = 0;
        if (((unsigned)iy < HH) & ((unsigned)ix < WW) & (r < NH))
            val = kgu[((bimg * HH + iy) * WW + ix) * 32 + c2];
        ldsu[KS_OFF / 2 + r * 36 + c2] = val;
    }
    __syncthreads();   // B1

    const int qd = lane >> 4, m = lane & 15;

    // ---- score MFMA: wave (mt,nh) -> rows mt*16.., n-tiles nh*5 .. +5 ----
    short8 qa[2];
    #pragma unroll
    for (int ks = 0; ks < 2; ++ks)
        qa[ks] = *reinterpret_cast<const short8*>(
            &lds[QS_OFF + (mt * 16 + m) * QS_STRIDE + ks * 32 + qd * 8]);

    f32x4 sc[5];
    #pragma unroll
    for (int n5 = 0; n5 < 5; ++n5) {
        const int nt = nh * 5 + n5;
        f32x4 a = {};
        #pragma unroll
        for (int ks = 0; ks < 2; ++ks) {
            const short8 bfr = *reinterpret_cast<const short8*>(
                &lds[KS_OFF + (nt * 16 + m) * KS_STRIDE + ks * 32 + qd * 8]);
            a = __builtin_amdgcn_mfma_f32_16x16x32_bf16(qa[ks], bfr, a, 0, 0, 0);
        }
        sc[n5] = a;
    }

    // ---- mask + per-half row max ----
    float mx[4] = {NEGBIG, NEGBIG, NEGBIG, NEGBIG};
    #pragma unroll
    for (int n5 = 0; n5 < 5; ++n5) {
        const int h  = (nh * 5 + n5) * 16 + m;
        const int hy = (h * 6554) >> 16;
        const int hx = h - hy * 10;
        const int iy = y0 - 3 + hy, ix = x0 - 3 + hx;
        const bool imgok = ((unsigned)iy < HH) & ((unsigned)ix < WW);
        #pragma unroll
        for (int r = 0; r < 4; ++r) {
            const int p  = mt * 16 + qd * 4 + r;
            const int py = p >> 2, px = p & 3;
            const bool ok = imgok & ((unsigned)(hy - py) <= 6u) & ((unsigned)(hx - px) <= 6u);
            const float s = ok ? sc[n5][r] * 0.125f : NEGBIG;
            sc[n5][r] = s;
            mx[r] = fmaxf(mx[r], s);
        }
    }
    #pragma unroll
    for (int r = 0; r < 4; ++r)
        #pragma unroll
        for (int off = 1; off < 16; off <<= 1)
            mx[r] = fmaxf(mx[r], __shfl_xor(mx[r], off));

    // ---- e = exp(s - mx_half), partial sums ----
    float sm[4] = {0.f, 0.f, 0.f, 0.f};
    #pragma unroll
    for (int n5 = 0; n5 < 5; ++n5)
        #pragma unroll
        for (int r = 0; r < 4; ++r) {
            const float s = sc[n5][r];
            const float e = (s > -1.0e38f) ? __expf(s - mx[r]) : 0.f;
            sc[n5][r] = e;
            sm[r] += e;
        }
    #pragma unroll
    for (int r = 0; r < 4; ++r)
        #pragma unroll
        for (int off = 1; off < 16; off <<= 1)
            sm[r] += __shfl_xor(sm[r], off);

    // ---- exchange partials across n-halves ----
    float* smf = reinterpret_cast<float*>(&lds[SM_OFF]);
    if (m == 0) {
        #pragma unroll
        for (int r = 0; r < 4; ++r) {
            const int row = qd * 4 + r;
            smf[(mt * 2 + nh) * 16 + row]      = mx[r];
            smf[64 + (mt * 2 + nh) * 16 + row] = sm[r];
        }
    }
    __syncthreads();   // B2 (also: QS/KS now dead)

    float fac[4];
    #pragma unroll
    for (int r = 0; r < 4; ++r) {
        const int row = qd * 4 + r;
        const float m0 = smf[(mt * 2 + 0) * 16 + row];
        const float m1 = smf[(mt * 2 + 1) * 16 + row];
        const float M  = fmaxf(m0, m1);
        const float s0 = smf[64 + (mt * 2 + 0) * 16 + row];
        const float s1 = smf[64 + (mt * 2 + 1) * 16 + row];
        const float S  = s0 * __expf(m0 - M) + s1 * __expf(m1 - M);
        fac[r] = __expf(mx[r] - M) / S;
    }

    // ---- write P quarter (bf16) ----
    #pragma unroll
    for (int n5 = 0; n5 < 5; ++n5)
        #pragma unroll
        for (int r = 0; r < 4; ++r) {
            const int row = mt * 16 + qd * 4 + r;
            const int col = (nh * 5 + n5) * 16 + m;
            lds[PS_OFF + row * PS_STRIDE + col] = f2bf(sc[n5][r] * fac[r]);
        }

    // ---- stage V^T (bf16 source), paired b32 writes ----
    {
        const int ch = tid & 127, half = tid >> 7;
        #pragma unroll 5
        for (int i = 0; i < 40; ++i) {
            const int r0 = half * 80 + i * 2;
            unsigned short v0 = 0, v1 = 0;
            {
                const int hy = (r0 * 6554) >> 16, hx = r0 - hy * 10;
                const int iy = y0 - 3 + hy, ix = x0 - 3 + hx;
                if (((unsigned)iy < HH) & ((unsigned)ix < WW) & (r0 < NH))
                    v0 = vbf[(size_t)((bimg * HH + iy) * WW + ix) * CC + ch];
            }
            {
                const int r1 = r0 + 1;
                const int hy = (r1 * 6554) >> 16, hx = r1 - hy * 10;
                const int iy = y0 - 3 + hy, ix = x0 - 3 + hx;
                if (((unsigned)iy < HH) & ((unsigned)ix < WW) & (r1 < NH))
                    v1 = vbf[(size_t)((bimg * HH + iy) * WW + ix) * CC + ch];
            }
            ldsu[(VT_OFF + ch * VT_STRIDE + r0) / 2] = (unsigned)v0 | ((unsigned)v1 << 16);
        }
    }
    __syncthreads();   // B3

    // ---- PV MFMA: att[mt rows, n-tiles nh*4..+4] ----
    short8 pa[5];
    #pragma unroll
    for (int ks = 0; ks < 5; ++ks)
        pa[ks] = *reinterpret_cast<const short8*>(
            &lds[PS_OFF + (mt * 16 + m) * PS_STRIDE + ks * 32 + qd * 8]);

    f32x4 oacc[4];
    #pragma unroll
    for (int n4 = 0; n4 < 4; ++n4) {
        const int nt = nh * 4 + n4;
        f32x4 a = {};
        #pragma unroll
        for (int ks = 0; ks < 5; ++ks) {
            const short8 bfr = *reinterpret_cast<const short8*>(
                &lds[VT_OFF + (nt * 16 + m) * VT_STRIDE + ks * 32 + qd * 8]);
            a = __builtin_amdgcn_mfma_f32_16x16x32_bf16(pa[ks], bfr, a, 0, 0, 0);
        }
        oacc[n4] = a;
    }

    // ---- att -> AS (own region, no hazard with PS/VT) ----
    #pragma unroll
    for (int n4 = 0; n4 < 4; ++n4)
        #pragma unroll
        for (int r = 0; r < 4; ++r) {
            const int row = mt * 16 + qd * 4 + r;
            const int col = (nh * 4 + n4) * 16 + m;
            lds[AS_OFF + row * AS_STRIDE + col] = f2bf(oacc[n4][r]);
        }
    __syncthreads();   // B4

    // ---- out-proj MFMA + bias + relu ----
    short8 aa[4];
    #pragma unroll
    for (int ks = 0; ks < 4; ++ks)
        aa[ks] = *reinterpret_cast<const short8*>(
            &lds[AS_OFF + (mt * 16 + m) * AS_STRIDE + ks * 32 + qd * 8]);

    #pragma unroll
    for (int n4 = 0; n4 < 4; ++n4) {
        const int nt = nh * 4 + n4;
        f32x4 a = {};
        #pragma unroll
        for (int ks = 0; ks < 4; ++ks) {
            const short8 bfr = *reinterpret_cast<const short8*>(
                WvT + (nt * 16 + m) * 128 + ks * 32 + qd * 8);
            a = __builtin_amdgcn_mfma_f32_16x16x32_bf16(aa[ks], bfr, a, 0, 0, 0);
        }
        const int col = nt * 16 + m;
        const float bb = bv[col];
        #pragma unroll
        for (int r = 0; r < 4; ++r) {
            const int p  = mt * 16 + qd * 4 + r;
            const int py = p >> 2, px = p & 3;
            const size_t gp = (size_t)(bimg * HH + y0 + py) * WW + (x0 + px);
            out[gp * OD + col] = fmaxf(a[r] + bb, 0.f);
        }
    }
}

extern "C" void kernel_launch(void* const* d_in, const int* in_sizes, int n_in,
                              void* d_out, int out_size, void* d_ws, size_t ws_size,
                              hipStream_t stream)
{
    const float* Q  = (const float*)d_in[0];
    const float* K  = (const float*)d_in[1];
    const float* V  = (const float*)d_in[2];
    const float* Wq = (const float*)d_in[3];
    const float* bq = (const float*)d_in[4];
    const float* Wk = (const float*)d_in[5];
    const float* bk = (const float*)d_in[6];
    const float* Wv = (const float*)d_in[7];
    const float* bv = (const float*)d_in[8];
    float* out = (float*)d_out;

    unsigned short* wbase = (unsigned short*)d_ws;
    unsigned short* WvT  = wbase + 16384;
    unsigned short* q_ws = wbase + 32768;                    // NPIX*64
    unsigned short* k_ws = q_ws + (size_t)NPIX * 64;         // NPIX*64
    unsigned short* v_bf = k_ws + (size_t)NPIX * 64;         // NPIX*128

    prep_kernel<<<1280, 256, 0, stream>>>(Wq, Wk, Wv, V, wbase, (unsigned*)v_bf);
    proj_kernel<<<576, 256, 0, stream>>>(Q, K, wbase, bq, bk, q_ws, k_ws);
    attn_kernel<<<576, 256, 0, stream>>>(q_ws, k_ws, v_bf, WvT, bv, out);
}

// Round 5
// 132.875 us; speedup vs baseline: 2.2039x; 1.0930x over previous
//
#include <hip/hip_runtime.h>
#include <math.h>

// Problem constants
#define BH 2
#define HH 96
#define WW 96
#define CC 128
#define NPIX (BH*HH*WW)

// Tile geometry
#define TH 8            // tile rows (pixels)
#define TW 4            // tile cols (pixels)  -> 32 px/block
#define NH 140          // real halo pixels: (8+6)*(4+6)
#define NHP 160         // padded halo rows

#define NEGBIG (-3.0e38f)

typedef __attribute__((ext_vector_type(8))) short short8;
typedef __attribute__((ext_vector_type(4))) float f32x4;

__device__ __forceinline__ unsigned short f2bf(float f) {
    union { float f; unsigned u; } a; a.f = f;
    return (unsigned short)((a.u + 0x7FFFu + ((a.u >> 16) & 1u)) >> 16);
}
__device__ __forceinline__ unsigned packbf(float x, float y) {
    return (unsigned)f2bf(x) | ((unsigned)f2bf(y) << 16);
}

// ---------------------------------------------------------------------------
// prep: weights fp32 -> transposed bf16; V fp32 -> bf16 (uint4 writes).
// ---------------------------------------------------------------------------
__global__ __launch_bounds__(256) void prep_kernel(
    const float* __restrict__ Wq, const float* __restrict__ Wk,
    const float* __restrict__ Wv, const float* __restrict__ V,
    unsigned short* __restrict__ wbase, uint4* __restrict__ vbf4)
{
    const int bid = blockIdx.x;
    const int tid = threadIdx.x;
    if (bid < 128) {
        unsigned short* WqT = wbase;
        unsigned short* WkT = wbase + 8192;
        unsigned short* WvT = wbase + 16384;
        const int e = bid * 256 + tid;                 // 0..32767
        if (e < 8192)       { WqT[e] = f2bf(Wq[(e & 127) * 64  + (e >> 7)]); }
        else if (e < 16384) { int t = e - 8192;  WkT[t] = f2bf(Wk[(t & 127) * 64  + (t >> 7)]); }
        else                { int t = e - 16384; WvT[t] = f2bf(Wv[(t & 127) * 128 + (t >> 7)]); }
    } else {
        const int idx = (bid - 128) * 256 + tid;       // 0..294911 (x8 floats)
        const float4* __restrict__ V4 = reinterpret_cast<const float4*>(V);
        const float4 a = V4[idx * 2], b = V4[idx * 2 + 1];
        uint4 o;
        o.x = packbf(a.x, a.y); o.y = packbf(a.z, a.w);
        o.z = packbf(b.x, b.y); o.w = packbf(b.z, b.w);
        vbf4[idx] = o;
    }
}

// ---------------------------------------------------------------------------
// Mega kernel: in-block q/k projection + neighborhood attention + out-proj.
// 576 blocks x 512 threads (8 waves). Wave = (mt = wv&1, ng = wv>>1).
// LDS (ushort idx):
//   PS  [32][168]  @ 0      (5376)   P matrix (bf16)
//   AS  [32][136]  @ 5376   (4352)   att (bf16)
//   SM  256 floats @ 9728   (512)    softmax partials (max, sum) x 4 groups
//   QP  [32][72]   @ 10240  (2304)   q-proj   } overlaid by
//   KP  [160][72]  @ 12544  (11520)  k-proj   } VT [128][168] @ 10240 (21504)
// total 31744 ushorts = 63488 B -> 2 blocks/CU, 16 waves/CU.
// ---------------------------------------------------------------------------
#define PS_OFF 0
#define PS_STRIDE 168
#define AS_OFF 5376
#define AS_STRIDE 136
#define SM_OFF 9728
#define QP_OFF 10240
#define KP_OFF 12544
#define PK_STRIDE 72
#define VT_OFF 10240
#define VT_STRIDE 168
#define LDS_N 31744

__global__ __launch_bounds__(512, 4) void attn_kernel(
    const float* __restrict__ Qg, const float* __restrict__ Kg,
    const unsigned short* __restrict__ vbf,
    const unsigned short* __restrict__ wbase,
    const float* __restrict__ bq, const float* __restrict__ bk,
    const float* __restrict__ bv, float* __restrict__ out)
{
    __shared__ unsigned short lds[LDS_N];
    const int tid  = threadIdx.x;
    const int lane = tid & 63;
    const int wv   = tid >> 6;     // 0..7
    const int mt   = wv & 1;
    const int ng   = wv >> 1;      // 0..3

    const int bid  = blockIdx.x;   // 576
    const int bimg = bid / 288;
    const int tidx = bid % 288;
    const int ty = tidx / 24, tx = tidx % 24;
    const int y0 = ty * TH, x0 = tx * TW;

    const int qd = lane >> 4, m = lane & 15;

    const unsigned short* __restrict__ WqT = wbase;
    const unsigned short* __restrict__ WkT = wbase + 8192;
    const unsigned short* __restrict__ WvT = wbase + 16384;

    // ================= Phase 1: q-proj (units 0,1) + k-proj (units 2..11) ===
    // unit u: u<2 -> q m-tile u; else k-halo m-tile (u-2). wave wv does
    // u = wv, and u = 8+wv if wv<4. All control wave-uniform.
    #pragma unroll
    for (int pass = 0; pass < 2; ++pass) {
        if (pass == 1 && wv >= 4) break;
        const int u = (pass == 0) ? wv : (8 + wv);
        const bool isq = (u < 2);

        // this lane's input row
        int gp = -1;
        if (isq) {
            const int p = u * 16 + m;
            const int py = p >> 2, px = p & 3;
            gp = (bimg * HH + y0 + py) * WW + (x0 + px);
        } else {
            const int h = (u - 2) * 16 + m;
            const int hy = (h * 6554) >> 16;          // h/10
            const int hx = h - hy * 10;
            const int iy = y0 - 3 + hy, ix = x0 - 3 + hx;
            if (((unsigned)iy < HH) & ((unsigned)ix < WW) & (h < NH))
                gp = (bimg * HH + iy) * WW + ix;
        }
        const float* __restrict__ Xg = isq ? Qg : Kg;

        short8 afr[4];
        if (gp >= 0) {
            #pragma unroll
            for (int ks = 0; ks < 4; ++ks) {
                const float4* __restrict__ src = reinterpret_cast<const float4*>(
                    Xg + (size_t)gp * 128 + ks * 32 + qd * 8);
                const float4 a0 = src[0], a1 = src[1];
                short8 f;
                f[0] = (short)f2bf(a0.x); f[1] = (short)f2bf(a0.y);
                f[2] = (short)f2bf(a0.z); f[3] = (short)f2bf(a0.w);
                f[4] = (short)f2bf(a1.x); f[5] = (short)f2bf(a1.y);
                f[6] = (short)f2bf(a1.z); f[7] = (short)f2bf(a1.w);
                afr[ks] = f;
            }
        } else {
            #pragma unroll
            for (int ks = 0; ks < 4; ++ks) {
                short8 f;
                #pragma unroll
                for (int j = 0; j < 8; ++j) f[j] = 0;
                afr[ks] = f;
            }
        }

        const unsigned short* __restrict__ WT = isq ? WqT : WkT;
        const float* __restrict__ bias = isq ? bq : bk;
        const int obase = isq ? (QP_OFF + u * 16 * PK_STRIDE)
                              : (KP_OFF + (u - 2) * 16 * PK_STRIDE);
        #pragma unroll
        for (int n = 0; n < 4; ++n) {
            f32x4 acc = {};
            #pragma unroll
            for (int ks = 0; ks < 4; ++ks) {
                const short8 bfr = *reinterpret_cast<const short8*>(
                    WT + (n * 16 + m) * 128 + ks * 32 + qd * 8);
                acc = __builtin_amdgcn_mfma_f32_16x16x32_bf16(afr[ks], bfr, acc, 0, 0, 0);
            }
            const int col = n * 16 + m;
            const float bb = bias[col];
            #pragma unroll
            for (int r = 0; r < 4; ++r)
                lds[obase + (qd * 4 + r) * PK_STRIDE + col] = f2bf(acc[r] + bb);
        }
    }
    __syncthreads();   // B1: QP/KP ready

    // ================= Phase 2: scores + softmax partials ===================
    // wave (mt, ng): n-tiles ng0:{0,1,2} ng1:{3,4,5} ng2:{6,7} ng3:{8,9}
    const int ntbase = (ng < 2) ? ng * 3 : 6 + (ng - 2) * 2;
    const int ntcnt  = (ng < 2) ? 3 : 2;

    short8 qa[2];
    #pragma unroll
    for (int ks = 0; ks < 2; ++ks)
        qa[ks] = *reinterpret_cast<const short8*>(
            &lds[QP_OFF + (mt * 16 + m) * PK_STRIDE + ks * 32 + qd * 8]);

    f32x4 sc[3];
    #pragma unroll
    for (int n5 = 0; n5 < 3; ++n5) {
        if (n5 >= ntcnt) break;
        const int nt = ntbase + n5;
        f32x4 a = {};
        #pragma unroll
        for (int ks = 0; ks < 2; ++ks) {
            const short8 bfr = *reinterpret_cast<const short8*>(
                &lds[KP_OFF + (nt * 16 + m) * PK_STRIDE + ks * 32 + qd * 8]);
            a = __builtin_amdgcn_mfma_f32_16x16x32_bf16(qa[ks], bfr, a, 0, 0, 0);
        }
        sc[n5] = a;
    }

    float mx[4] = {NEGBIG, NEGBIG, NEGBIG, NEGBIG};
    #pragma unroll
    for (int n5 = 0; n5 < 3; ++n5) {
        if (n5 >= ntcnt) break;
        const int h  = (ntbase + n5) * 16 + m;
        const int hy = (h * 6554) >> 16;
        const int hx = h - hy * 10;
        const int iy = y0 - 3 + hy, ix = x0 - 3 + hx;
        const bool imgok = ((unsigned)iy < HH) & ((unsigned)ix < WW);
        #pragma unroll
        for (int r = 0; r < 4; ++r) {
            const int p  = mt * 16 + qd * 4 + r;
            const int py = p >> 2, px = p & 3;
            const bool ok = imgok & ((unsigned)(hy - py) <= 6u) & ((unsigned)(hx - px) <= 6u);
            const float s = ok ? sc[n5][r] * 0.125f : NEGBIG;
            sc[n5][r] = s;
            mx[r] = fmaxf(mx[r], s);
        }
    }
    #pragma unroll
    for (int r = 0; r < 4; ++r)
        #pragma unroll
        for (int off = 1; off < 16; off <<= 1)
            mx[r] = fmaxf(mx[r], __shfl_xor(mx[r], off));

    float sm[4] = {0.f, 0.f, 0.f, 0.f};
    #pragma unroll
    for (int n5 = 0; n5 < 3; ++n5) {
        if (n5 >= ntcnt) break;
        #pragma unroll
        for (int r = 0; r < 4; ++r) {
            const float s = sc[n5][r];
            const float e = (s > -1.0e38f) ? __expf(s - mx[r]) : 0.f;
            sc[n5][r] = e;
            sm[r] += e;
        }
    }
    #pragma unroll
    for (int r = 0; r < 4; ++r)
        #pragma unroll
        for (int off = 1; off < 16; off <<= 1)
            sm[r] += __shfl_xor(sm[r], off);

    float* __restrict__ smf = reinterpret_cast<float*>(&lds[SM_OFF]);
    if (m == 0) {
        #pragma unroll
        for (int r = 0; r < 4; ++r) {
            const int row = mt * 16 + qd * 4 + r;
            smf[row * 4 + ng]       = mx[r];
            smf[128 + row * 4 + ng] = sm[r];
        }
    }
    __syncthreads();   // B2: partials ready; QP/KP dead

    // merge 4-way partials
    float fac[4];
    #pragma unroll
    for (int r = 0; r < 4; ++r) {
        const int row = mt * 16 + qd * 4 + r;
        float M = smf[row * 4 + 0];
        M = fmaxf(M, smf[row * 4 + 1]);
        M = fmaxf(M, smf[row * 4 + 2]);
        M = fmaxf(M, smf[row * 4 + 3]);
        float S = 0.f;
        #pragma unroll
        for (int g = 0; g < 4; ++g) {
            const float mg = smf[row * 4 + g];
            const float eg = (mg > -1.0e38f) ? __expf(mg - M) : 0.f;
            S += smf[128 + row * 4 + g] * eg;
        }
        const float eo = (mx[r] > -1.0e38f) ? __expf(mx[r] - M) : 0.f;
        fac[r] = eo / S;
    }

    // write P quarter (bf16)
    #pragma unroll
    for (int n5 = 0; n5 < 3; ++n5) {
        if (n5 >= ntcnt) break;
        #pragma unroll
        for (int r = 0; r < 4; ++r) {
            const int row = mt * 16 + qd * 4 + r;
            const int col = (ntbase + n5) * 16 + m;
            lds[PS_OFF + row * PS_STRIDE + col] = f2bf(sc[n5][r] * fac[r]);
        }
    }

    // stage V^T (bf16), paired b32 writes; pad rows -> 0
    {
        unsigned* ldsu = reinterpret_cast<unsigned*>(lds);
        const int ch = tid & 127, q4 = tid >> 7;     // quarter 0..3
        #pragma unroll 5
        for (int i = 0; i < 20; ++i) {
            const int r0 = q4 * 40 + i * 2;
            unsigned short v0 = 0, v1 = 0;
            {
                const int hy = (r0 * 6554) >> 16, hx = r0 - hy * 10;
                const int iy = y0 - 3 + hy, ix = x0 - 3 + hx;
                if (((unsigned)iy < HH) & ((unsigned)ix < WW) & (r0 < NH))
                    v0 = vbf[(size_t)((bimg * HH + iy) * WW + ix) * CC + ch];
            }
            {
                const int r1 = r0 + 1;
                const int hy = (r1 * 6554) >> 16, hx = r1 - hy * 10;
                const int iy = y0 - 3 + hy, ix = x0 - 3 + hx;
                if (((unsigned)iy < HH) & ((unsigned)ix < WW) & (r1 < NH))
                    v1 = vbf[(size_t)((bimg * HH + iy) * WW + ix) * CC + ch];
            }
            ldsu[(VT_OFF + ch * VT_STRIDE + r0) / 2] = (unsigned)v0 | ((unsigned)v1 << 16);
        }
    }
    __syncthreads();   // B3: P + V^T ready

    // ================= Phase 3: PV =========================================
    short8 pa[5];
    #pragma unroll
    for (int ks = 0; ks < 5; ++ks)
        pa[ks] = *reinterpret_cast<const short8*>(
            &lds[PS_OFF + (mt * 16 + m) * PS_STRIDE + ks * 32 + qd * 8]);

    f32x4 oacc[2];
    #pragma unroll
    for (int n2 = 0; n2 < 2; ++n2) {
        const int nt = ng * 2 + n2;
        f32x4 a = {};
        #pragma unroll
        for (int ks = 0; ks < 5; ++ks) {
            const short8 bfr = *reinterpret_cast<const short8*>(
                &lds[VT_OFF + (nt * 16 + m) * VT_STRIDE + ks * 32 + qd * 8]);
            a = __builtin_amdgcn_mfma_f32_16x16x32_bf16(pa[ks], bfr, a, 0, 0, 0);
        }
        oacc[n2] = a;
    }

    // att -> AS (separate region, no hazard)
    #pragma unroll
    for (int n2 = 0; n2 < 2; ++n2)
        #pragma unroll
        for (int r = 0; r < 4; ++r) {
            const int row = mt * 16 + qd * 4 + r;
            const int col = (ng * 2 + n2) * 16 + m;
            lds[AS_OFF + row * AS_STRIDE + col] = f2bf(oacc[n2][r]);
        }
    __syncthreads();   // B4: att ready

    // ================= Phase 4: out-proj + bias + relu ======================
    short8 aa[4];
    #pragma unroll
    for (int ks = 0; ks < 4; ++ks)
        aa[ks] = *reinterpret_cast<const short8*>(
            &lds[AS_OFF + (mt * 16 + m) * AS_STRIDE + ks * 32 + qd * 8]);

    #pragma unroll
    for (int n2 = 0; n2 < 2; ++n2) {
        const int nt = ng * 2 + n2;
        f32x4 a = {};
        #pragma unroll
        for (int ks = 0; ks < 4; ++ks) {
            const short8 bfr = *reinterpret_cast<const short8*>(
                WvT + (nt * 16 + m) * 128 + ks * 32 + qd * 8);
            a = __builtin_amdgcn_mfma_f32_16x16x32_bf16(aa[ks], bfr, a, 0, 0, 0);
        }
        const int col = nt * 16 + m;
        const float bb = bv[col];
        #pragma unroll
        for (int r = 0; r < 4; ++r) {
            const int p  = mt * 16 + qd * 4 + r;
            const int py = p >> 2, px = p & 3;
            const size_t gp = (size_t)(bimg * HH + y0 + py) * WW + (x0 + px);
            out[gp * 128 + col] = fmaxf(a[r] + bb, 0.f);
        }
    }
}

extern "C" void kernel_launch(void* const* d_in, const int* in_sizes, int n_in,
                              void* d_out, int out_size, void* d_ws, size_t ws_size,
                              hipStream_t stream)
{
    const float* Q  = (const float*)d_in[0];
    const float* K  = (const float*)d_in[1];
    const float* V  = (const float*)d_in[2];
    const float* Wq = (const float*)d_in[3];
    const float* bq = (const float*)d_in[4];
    const float* Wk = (const float*)d_in[5];
    const float* bk = (const float*)d_in[6];
    const float* Wv = (const float*)d_in[7];
    const float* bv = (const float*)d_in[8];
    float* out = (float*)d_out;

    unsigned short* wbase = (unsigned short*)d_ws;           // 32768 ushorts (64 KB)
    unsigned short* v_bf  = wbase + 32768;                   // NPIX*128 bf16 (4.7 MB)

    prep_kernel<<<1280, 256, 0, stream>>>(Wq, Wk, Wv, V, wbase, (uint4*)v_bf);
    attn_kernel<<<576, 512, 0, stream>>>(Q, K, v_bf, wbase, bq, bk, bv, out);
}

// Round 6
// 110.790 us; speedup vs baseline: 2.6432x; 1.1993x over previous
//
#include <hip/hip_runtime.h>
#include <math.h>

// Problem constants
#define BH 2
#define HH 96
#define WW 96
#define CC 128
#define NPIX (BH*HH*WW)

// Tile geometry
#define TH 8            // tile rows (pixels)
#define TW 4            // tile cols (pixels)  -> 32 px/block
#define NH 140          // real halo pixels: (8+6)*(4+6)
#define NHP 160         // padded halo rows

#define NEGBIG (-3.0e38f)

typedef __attribute__((ext_vector_type(8))) short short8;
typedef __attribute__((ext_vector_type(4))) float f32x4;

__device__ __forceinline__ unsigned short f2bf(float f) {
    union { float f; unsigned u; } a; a.f = f;
    return (unsigned short)((a.u + 0x7FFFu + ((a.u >> 16) & 1u)) >> 16);
}
__device__ __forceinline__ unsigned packbf(float x, float y) {
    return (unsigned)f2bf(x) | ((unsigned)f2bf(y) << 16);
}

// ---------------------------------------------------------------------------
// Dispatch 1: everything that feeds the attention kernel.
//   blocks 0..575     : q/k projection -> q_bf/k_bf [NPIX][64] bf16
//                       (4 indep waves/block, MFMA, W gathered from fp32)
//   blocks 576..1727  : V fp32 -> v_bf [NPIX][128] bf16 (uint4 writes)
//   blocks 1728..1743 : Wv fp32 -> WvT [128][128] bf16 (transposed)
// ---------------------------------------------------------------------------
__global__ __launch_bounds__(256) void prep_proj_kernel(
    const float* __restrict__ Qg, const float* __restrict__ Kg,
    const float* __restrict__ V,  const float* __restrict__ Wq,
    const float* __restrict__ bq, const float* __restrict__ Wk,
    const float* __restrict__ bk, const float* __restrict__ Wv,
    unsigned short* __restrict__ q_bf, unsigned short* __restrict__ k_bf,
    unsigned short* __restrict__ v_bf, unsigned short* __restrict__ WvT)
{
    const int bid = blockIdx.x;
    const int tid = threadIdx.x;

    if (bid < 576) {
        const int lane = tid & 63;
        const int wvv  = tid >> 6;
        const int gw   = bid * 4 + wvv;            // 0..2303
        const bool isq = gw < 1152;
        const int row0 = (isq ? gw : gw - 1152) * 16;

        const float* __restrict__ X   = isq ? Qg : Kg;
        const float* __restrict__ Wt  = isq ? Wq : Wk;
        const float* __restrict__ bia = isq ? bq : bk;
        unsigned short* __restrict__ Y = isq ? q_bf : k_bf;

        const int qd = lane >> 4, m = lane & 15;

        // A-frags: 4 k-steps, direct fp32 loads + convert
        short8 afr[4];
        #pragma unroll
        for (int ks = 0; ks < 4; ++ks) {
            const float4* __restrict__ src = reinterpret_cast<const float4*>(
                X + (size_t)(row0 + m) * 128 + ks * 32 + qd * 8);
            const float4 a0 = src[0], a1 = src[1];
            short8 f;
            f[0] = (short)f2bf(a0.x); f[1] = (short)f2bf(a0.y);
            f[2] = (short)f2bf(a0.z); f[3] = (short)f2bf(a0.w);
            f[4] = (short)f2bf(a1.x); f[5] = (short)f2bf(a1.y);
            f[6] = (short)f2bf(a1.z); f[7] = (short)f2bf(a1.w);
            afr[ks] = f;
        }

        #pragma unroll
        for (int n = 0; n < 4; ++n) {
            f32x4 acc = {};
            #pragma unroll
            for (int ks = 0; ks < 4; ++ks) {
                // B-frag: 8 gathers of W[k][n*16+m], k = ks*32+qd*8+j
                short8 bfr;
                #pragma unroll
                for (int j = 0; j < 8; ++j)
                    bfr[j] = (short)f2bf(Wt[(ks * 32 + qd * 8 + j) * 64 + n * 16 + m]);
                acc = __builtin_amdgcn_mfma_f32_16x16x32_bf16(afr[ks], bfr, acc, 0, 0, 0);
            }
            const int col = n * 16 + m;
            const float bb = bia[col];
            #pragma unroll
            for (int r = 0; r < 4; ++r)
                Y[(size_t)(row0 + qd * 4 + r) * 64 + col] = f2bf(acc[r] + bb);
        }
    } else if (bid < 1728) {
        // V convert: 1152 blocks x 256 thr x 8 floats
        const int idx = (bid - 576) * 256 + tid;          // 0..294911
        const float4* __restrict__ V4 = reinterpret_cast<const float4*>(V);
        const float4 a = V4[idx * 2], b = V4[idx * 2 + 1];
        uint4 o;
        o.x = packbf(a.x, a.y); o.y = packbf(a.z, a.w);
        o.z = packbf(b.x, b.y); o.w = packbf(b.z, b.w);
        reinterpret_cast<uint4*>(v_bf)[idx] = o;
    } else {
        // WvT transpose: 16 blocks x 256 thr x 4 elems
        const int base = (bid - 1728) * 1024 + tid * 4;
        #pragma unroll
        for (int i = 0; i < 4; ++i) {
            const int e = base + i;                        // e = n*128 + k
            WvT[e] = f2bf(Wv[(e & 127) * 128 + (e >> 7)]);
        }
    }
}

// ---------------------------------------------------------------------------
// Dispatch 2: neighborhood attention + out-projection, LDS-light.
// 576 blocks x 256 thr (4 waves: mt = wv&1 row-half, ng = wv>>1 col-half).
// B-frags come straight from global (L2/L3-hot): k_bf rows (score),
// v_bf u16 gathers (PV), WvT rows (out-proj). LDS only for P, att,
// softmax partials, and the halo->pixel offset table.
// ---------------------------------------------------------------------------
#define PS_OFF 0
#define PS_STRIDE 168      // 32 x 168 = 5376
#define AS_OFF 5376
#define AS_STRIDE 136      // 32 x 136 = 4352 -> 9728
#define SM_OFF 9728        // 128 floats = 256 sh -> 9984
#define OFF_OFF 9984       // 160 ints  = 320 sh -> 10304
#define LDS_N 10304        // 20608 B

__global__ __launch_bounds__(256) void attn_kernel(
    const unsigned short* __restrict__ q_bf, const unsigned short* __restrict__ k_bf,
    const unsigned short* __restrict__ v_bf, const unsigned short* __restrict__ WvT,
    const float* __restrict__ bv, float* __restrict__ out)
{
    __shared__ unsigned short lds[LDS_N];
    const int tid  = threadIdx.x;
    const int lane = tid & 63;
    const int wv   = tid >> 6;
    const int mt   = wv & 1;
    const int ng   = wv >> 1;      // 0..1

    const int bid  = blockIdx.x;   // 576
    const int bimg = bid / 288;
    const int tidx = bid % 288;
    const int ty = tidx / 24, tx = tidx % 24;
    const int y0 = ty * TH, x0 = tx * TW;

    const int qd = lane >> 4, m = lane & 15;

    int* __restrict__ offsI = reinterpret_cast<int*>(&lds[OFF_OFF]);
    float* __restrict__ smf = reinterpret_cast<float*>(&lds[SM_OFF]);

    // ---- Phase 0: halo -> global pixel offset table (-1 = invalid) ----
    if (tid < NHP) {
        const int r = tid;
        const int hy = (r * 6554) >> 16;            // r / 10
        const int hx = r - hy * 10;
        const int iy = y0 - 3 + hy, ix = x0 - 3 + hx;
        int o = -1;
        if (((unsigned)iy < HH) & ((unsigned)ix < WW) & (r < NH))
            o = (bimg * HH + iy) * WW + ix;
        offsI[r] = o;
    }
    __syncthreads();   // B1

    // ---- Phase 1: scores (5 n-tiles per wave) ----
    short8 qa[2];
    {
        const int p  = mt * 16 + m;
        const int py = p >> 2, px = p & 3;
        const size_t gq = (size_t)(bimg * HH + y0 + py) * WW + (x0 + px);
        #pragma unroll
        for (int ks = 0; ks < 2; ++ks)
            qa[ks] = *reinterpret_cast<const short8*>(q_bf + gq * 64 + ks * 32 + qd * 8);
    }

    f32x4 sc[5];
    int offh[5];
    #pragma unroll
    for (int n5 = 0; n5 < 5; ++n5) {
        const int nt = ng * 5 + n5;
        const int oh = offsI[nt * 16 + m];
        offh[n5] = oh;
        const size_t ob = (size_t)(oh < 0 ? 0 : oh) * 64;
        f32x4 a = {};
        #pragma unroll
        for (int ks = 0; ks < 2; ++ks) {
            const short8 bfr = *reinterpret_cast<const short8*>(k_bf + ob + ks * 32 + qd * 8);
            a = __builtin_amdgcn_mfma_f32_16x16x32_bf16(qa[ks], bfr, a, 0, 0, 0);
        }
        sc[n5] = a;
    }

    // ---- mask + row max ----
    float mx[4] = {NEGBIG, NEGBIG, NEGBIG, NEGBIG};
    #pragma unroll
    for (int n5 = 0; n5 < 5; ++n5) {
        const int h  = (ng * 5 + n5) * 16 + m;
        const int hy = (h * 6554) >> 16;
        const int hx = h - hy * 10;
        const bool imgok = offh[n5] >= 0;
        #pragma unroll
        for (int r = 0; r < 4; ++r) {
            const int p  = mt * 16 + qd * 4 + r;
            const int py = p >> 2, px = p & 3;
            const bool ok = imgok & ((unsigned)(hy - py) <= 6u) & ((unsigned)(hx - px) <= 6u);
            const float s = ok ? sc[n5][r] * 0.125f : NEGBIG;
            sc[n5][r] = s;
            mx[r] = fmaxf(mx[r], s);
        }
    }
    #pragma unroll
    for (int r = 0; r < 4; ++r)
        #pragma unroll
        for (int off = 1; off < 16; off <<= 1)
            mx[r] = fmaxf(mx[r], __shfl_xor(mx[r], off));

    float sm[4] = {0.f, 0.f, 0.f, 0.f};
    #pragma unroll
    for (int n5 = 0; n5 < 5; ++n5)
        #pragma unroll
        for (int r = 0; r < 4; ++r) {
            const float s = sc[n5][r];
            const float e = (s > -1.0e38f) ? __expf(s - mx[r]) : 0.f;
            sc[n5][r] = e;
            sm[r] += e;
        }
    #pragma unroll
    for (int r = 0; r < 4; ++r)
        #pragma unroll
        for (int off = 1; off < 16; off <<= 1)
            sm[r] += __shfl_xor(sm[r], off);

    if (m == 0) {
        #pragma unroll
        for (int r = 0; r < 4; ++r) {
            const int row = mt * 16 + qd * 4 + r;
            smf[row * 2 + ng]      = mx[r];
            smf[64 + row * 2 + ng] = sm[r];
        }
    }
    __syncthreads();   // B2

    float fac[4];
    #pragma unroll
    for (int r = 0; r < 4; ++r) {
        const int row = mt * 16 + qd * 4 + r;
        const float m0 = smf[row * 2 + 0];
        const float m1 = smf[row * 2 + 1];
        const float M  = fmaxf(m0, m1);
        const float s0 = smf[64 + row * 2 + 0];
        const float s1 = smf[64 + row * 2 + 1];
        const float S  = s0 * __expf(m0 - M) + s1 * __expf(m1 - M);
        fac[r] = __expf(mx[r] - M) / S;
    }

    // write P quarter (bf16)
    #pragma unroll
    for (int n5 = 0; n5 < 5; ++n5)
        #pragma unroll
        for (int r = 0; r < 4; ++r) {
            const int row = mt * 16 + qd * 4 + r;
            const int col = (ng * 5 + n5) * 16 + m;
            lds[PS_OFF + row * PS_STRIDE + col] = f2bf(sc[n5][r] * fac[r]);
        }
    __syncthreads();   // B3: P complete

    // ---- Phase 2: PV via global v_bf gathers ----
    short8 pa[5];
    #pragma unroll
    for (int ks = 0; ks < 5; ++ks)
        pa[ks] = *reinterpret_cast<const short8*>(
            &lds[PS_OFF + (mt * 16 + m) * PS_STRIDE + ks * 32 + qd * 8]);

    f32x4 oacc[4] = {};
    #pragma unroll
    for (int ks = 0; ks < 5; ++ks) {
        // 8 halo rows for this (ks, qd)
        const unsigned short* vbase[8];
        #pragma unroll
        for (int j = 0; j < 8; ++j) {
            const int o = offsI[ks * 32 + qd * 8 + j];
            vbase[j] = v_bf + (size_t)(o < 0 ? 0 : o) * 128;
        }
        #pragma unroll
        for (int n4 = 0; n4 < 4; ++n4) {
            const int ch = (ng * 4 + n4) * 16 + m;
            short8 bfr;
            #pragma unroll
            for (int j = 0; j < 8; ++j)
                bfr[j] = (short)vbase[j][ch];
            oacc[n4] = __builtin_amdgcn_mfma_f32_16x16x32_bf16(pa[ks], bfr, oacc[n4], 0, 0, 0);
        }
    }

    // att -> AS
    #pragma unroll
    for (int n4 = 0; n4 < 4; ++n4)
        #pragma unroll
        for (int r = 0; r < 4; ++r) {
            const int row = mt * 16 + qd * 4 + r;
            const int col = (ng * 4 + n4) * 16 + m;
            lds[AS_OFF + row * AS_STRIDE + col] = f2bf(oacc[n4][r]);
        }
    __syncthreads();   // B4: att complete

    // ---- Phase 3: out-proj + bias + relu ----
    short8 aa[4];
    #pragma unroll
    for (int ks = 0; ks < 4; ++ks)
        aa[ks] = *reinterpret_cast<const short8*>(
            &lds[AS_OFF + (mt * 16 + m) * AS_STRIDE + ks * 32 + qd * 8]);

    #pragma unroll
    for (int n4 = 0; n4 < 4; ++n4) {
        const int nt = ng * 4 + n4;
        f32x4 a = {};
        #pragma unroll
        for (int ks = 0; ks < 4; ++ks) {
            const short8 bfr = *reinterpret_cast<const short8*>(
                WvT + (nt * 16 + m) * 128 + ks * 32 + qd * 8);
            a = __builtin_amdgcn_mfma_f32_16x16x32_bf16(aa[ks], bfr, a, 0, 0, 0);
        }
        const int col = nt * 16 + m;
        const float bb = bv[col];
        #pragma unroll
        for (int r = 0; r < 4; ++r) {
            const int p  = mt * 16 + qd * 4 + r;
            const int py = p >> 2, px = p & 3;
            const size_t gp = (size_t)(bimg * HH + y0 + py) * WW + (x0 + px);
            out[gp * 128 + col] = fmaxf(a[r] + bb, 0.f);
        }
    }
}

extern "C" void kernel_launch(void* const* d_in, const int* in_sizes, int n_in,
                              void* d_out, int out_size, void* d_ws, size_t ws_size,
                              hipStream_t stream)
{
    const float* Q  = (const float*)d_in[0];
    const float* K  = (const float*)d_in[1];
    const float* V  = (const float*)d_in[2];
    const float* Wq = (const float*)d_in[3];
    const float* bq = (const float*)d_in[4];
    const float* Wk = (const float*)d_in[5];
    const float* bk = (const float*)d_in[6];
    const float* Wv = (const float*)d_in[7];
    const float* bv = (const float*)d_in[8];
    float* out = (float*)d_out;

    unsigned short* WvT  = (unsigned short*)d_ws;              // 16384 sh
    unsigned short* q_bf = WvT + 16384;                        // NPIX*64
    unsigned short* k_bf = q_bf + (size_t)NPIX * 64;           // NPIX*64
    unsigned short* v_bf = k_bf + (size_t)NPIX * 64;           // NPIX*128

    prep_proj_kernel<<<1744, 256, 0, stream>>>(Q, K, V, Wq, bq, Wk, bk, Wv,
                                               q_bf, k_bf, v_bf, WvT);
    attn_kernel<<<576, 256, 0, stream>>>(q_bf, k_bf, v_bf, WvT, bv, out);
}